// Round 7
// baseline (135.716 us; speedup 1.0000x reference)
//
#include <hip/hip_runtime.h>
#include <stdint.h>

typedef _Float16 half_t;
typedef _Float16 half8 __attribute__((ext_vector_type(8)));
typedef __fp16 fp16x2 __attribute__((ext_vector_type(2)));
typedef float floatx4 __attribute__((ext_vector_type(4)));
typedef float floatx16 __attribute__((ext_vector_type(16)));
typedef unsigned int uint;
typedef unsigned int uint4v __attribute__((ext_vector_type(4)));

#define LOG2E 1.4426950408889634f

__device__ __forceinline__ void gload_lds16(const void* g, void* l) {
  __builtin_amdgcn_global_load_lds(
      (__attribute__((address_space(1))) void*)(uintptr_t)g,
      (__attribute__((address_space(3))) void*)(uintptr_t)l, 16, 0, 0);
}

// involution swizzles: XOR byte bits 4..6 with low row bits (keeps 16B alignment)
__device__ __forceinline__ int swz64(int b)  { return b ^ (((b >> 7) & 3) << 4); }   // 64B rows
__device__ __forceinline__ int swz128(int b) { return b ^ (((b >> 7) & 7) << 4); }   // 128B rows

__device__ __forceinline__ uint pkrtz(float a, float b) {
  union { fp16x2 h; uint u; } cv;
  cv.h = __builtin_amdgcn_cvt_pkrtz(a, b);
  return cv.u;
}
__device__ __forceinline__ void pl32swap(uint &x, uint &y) {
  asm("v_permlane32_swap_b32 %0, %1" : "+v"(x), "+v"(y));
}
__device__ __forceinline__ half8 as_h8(uint4v v) {
  union { uint4v u; half8 h; } c; c.u = v; return c.h;
}

// ---------------- fp32 -> fp16 converts ----------------
__global__ void cvt_x_kernel(const float* __restrict__ X, half_t* __restrict__ X16) {
  int i = (blockIdx.x * 256 + threadIdx.x) * 8;
  float4 u = *(const float4*)(X + i);
  float4 v = *(const float4*)(X + i + 4);
  half8 o = {(half_t)u.x, (half_t)u.y, (half_t)u.z, (half_t)u.w,
             (half_t)v.x, (half_t)v.y, (half_t)v.z, (half_t)v.w};
  *(half8*)(X16 + i) = o;
}

__global__ void cvt_w_kernel(const float* __restrict__ Wq, const float* __restrict__ Wk,
                             const float* __restrict__ Wv, const float* __restrict__ Wo,
                             half_t* __restrict__ W16) {
  int i = blockIdx.x * 256 + threadIdx.x;
  int widx = i >> 15;
  int j = (i & 32767) * 8;
  const float* src = (widx == 0) ? Wq : (widx == 1) ? Wk : (widx == 2) ? Wv : Wo;
  float sc = (widx == 0) ? 0.125f * LOG2E : 1.0f;  // fold 1/sqrt(64) AND log2(e) into Wq
  float4 u = *(const float4*)(src + j);
  float4 v = *(const float4*)(src + j + 4);
  half8 o = {(half_t)(u.x * sc), (half_t)(u.y * sc), (half_t)(u.z * sc), (half_t)(u.w * sc),
             (half_t)(v.x * sc), (half_t)(v.y * sc), (half_t)(v.z * sc), (half_t)(v.w * sc)};
  *(half8*)(W16 + widx * 262144 + j) = o;
}

// ---------------- NT fp16 GEMM, 128x128 tile, BK=32, K=512 ----------------
template <int MODE>
__global__ __launch_bounds__(256) void gemm_nt(
    const half_t* __restrict__ A, const half_t* __restrict__ B0,
    const half_t* __restrict__ B1, half_t* __restrict__ outh,
    half_t* __restrict__ outh2, float* __restrict__ outf,
    const float* __restrict__ bias) {
  __shared__ __attribute__((aligned(16))) half_t As[128 * 32];
  __shared__ __attribute__((aligned(16))) half_t Bs[128 * 32];

  const int tid = threadIdx.x;
  const int w = tid >> 6, l = tid & 63, g = l >> 4, c = l & 15;
  const int wr = w >> 1, wc = w & 1;
  const int bidx = blockIdx.x;

  int rt, ct;
  const half_t *Ab, *Bb;
  if (MODE == 0) {
    rt = bidx >> 3; ct = bidx & 7;
    Ab = A + (size_t)rt * 128 * 512;
    Bb = ((ct < 4) ? B0 : B1) + (size_t)(ct & 3) * 128 * 512;
  } else if (MODE == 1) {
    rt = bidx >> 6; ct = bidx & 63;
    Ab = A + (size_t)rt * 128 * 512;
    Bb = B0 + (size_t)ct * 128 * 512;
  } else {
    rt = bidx >> 2; ct = bidx & 3;
    Ab = A + (size_t)rt * 128 * 512;
    Bb = B0 + (size_t)ct * 128 * 512;
  }

  const floatx4 fzero = {0.f, 0.f, 0.f, 0.f};
  floatx4 acc[4][4];
#pragma unroll
  for (int m = 0; m < 4; ++m)
#pragma unroll
    for (int n = 0; n < 4; ++n) acc[m][n] = fzero;

  for (int kt = 0; kt < 16; ++kt) {
    __syncthreads();
#pragma unroll
    for (int i = 0; i < 2; ++i) {
      int rel = i * 4096 + tid * 16;
      int lg = swz64(rel);
      int row = lg >> 6, inner = (lg & 63) >> 1;
      gload_lds16(Ab + (size_t)row * 512 + kt * 32 + inner, As + (rel >> 1));
      gload_lds16(Bb + (size_t)row * 512 + kt * 32 + inner, Bs + (rel >> 1));
    }
    __syncthreads();
    half8 a[4], b[4];
#pragma unroll
    for (int m = 0; m < 4; ++m)
      a[m] = *(const half8*)&As[swz64(((wr * 64 + m * 16 + c) << 6) + (g << 4)) >> 1];
#pragma unroll
    for (int n = 0; n < 4; ++n)
      b[n] = *(const half8*)&Bs[swz64(((wc * 64 + n * 16 + c) << 6) + (g << 4)) >> 1];
#pragma unroll
    for (int m = 0; m < 4; ++m)
#pragma unroll
      for (int n = 0; n < 4; ++n)
        acc[m][n] = __builtin_amdgcn_mfma_f32_16x16x32_f16(a[m], b[n], acc[m][n], 0, 0, 0);
  }

  const int r0 = wr * 64, c0 = wc * 64;
  if (MODE == 0) {
    half_t* O = ((ct < 4) ? outh : outh2) + (size_t)rt * 128 * 512 + (size_t)(ct & 3) * 128;
#pragma unroll
    for (int m = 0; m < 4; ++m)
#pragma unroll
      for (int j = 0; j < 4; ++j)
#pragma unroll
        for (int n = 0; n < 4; ++n)
          O[(size_t)(r0 + m * 16 + g * 4 + j) * 512 + c0 + n * 16 + c] = (half_t)acc[m][n][j];
  } else if (MODE == 1) {
    half_t* O = outh + (size_t)(ct >> 5) * 2097152 + (size_t)(ct & 31) * 128;
#pragma unroll
    for (int m = 0; m < 4; ++m)
#pragma unroll
      for (int j = 0; j < 4; ++j)
#pragma unroll
        for (int n = 0; n < 4; ++n)
          O[(size_t)(rt * 128 + r0 + m * 16 + g * 4 + j) * 4096 + c0 + n * 16 + c] =
              (half_t)acc[m][n][j];
  } else {
    float* O = outf + (size_t)rt * 128 * 512 + ct * 128;
    float bv[4];
#pragma unroll
    for (int n = 0; n < 4; ++n) bv[n] = bias[ct * 128 + c0 + n * 16 + c];
#pragma unroll
    for (int m = 0; m < 4; ++m)
#pragma unroll
      for (int j = 0; j < 4; ++j)
#pragma unroll
        for (int n = 0; n < 4; ++n)
          O[(size_t)(r0 + m * 16 + g * 4 + j) * 512 + c0 + n * 16 + c] = acc[m][n][j] + bv[n];
  }
}

// ---------------- flash attention v6 ----------------
// v3 (verified) with ONE structural change: KVBLK 128 -> 64 (LDS 64KB -> 33KB,
// 2 -> 4 blocks/CU). QBLK=128, 4 waves 2x2 (kw=w>>1, qw=w&1) as in v3.
// 32x32x16 MFMA, swapped QK^T, in-register P (cvt_pkrtz + permlane32_swap),
// no-max softmax, double-buffered K/V, 1 barrier/tile, XCD swizzle.
__global__ __launch_bounds__(256, 2) void attn_kernel(
    const half_t* __restrict__ Q16, const half_t* __restrict__ K16,
    const half_t* __restrict__ Vt, half_t* __restrict__ O16) {
  // unified 33KB LDS: [0,16K) K dbuf (2x8KB), [16K,32K) V dbuf (2x8KB);
  // epilogue reuses [0,32K) as red, [32K,33K) as redl.
  __shared__ __attribute__((aligned(16))) char smem[33 * 1024];
  half_t* kb_lds = (half_t*)smem;            // [buf][64 key][64 d], 128B rows
  half_t* vb_lds = (half_t*)(smem + 16384);  // [buf][64 d][64 key], 128B rows

  const int tid = threadIdx.x;
  const int w = tid >> 6, l = tid & 63, lo = l & 31, h = l >> 5;
  const int kw = w >> 1, qw = w & 1;
  // bijective XCD swizzle: 512 blocks -> chunks of 64 per XCD
  const int bid = (blockIdx.x & 7) * 64 + (blockIdx.x >> 3);
  const int bh = bid >> 5, qt = bid & 31;
  const int b = bh >> 3, hh = bh & 7;

  const half_t* Qb = Q16 + (size_t)(b * 4096 + qt * 128 + qw * 64) * 512 + hh * 64;
  const half_t* Kb = K16 + (size_t)b * 4096 * 512 + hh * 64;
  const half_t* Vb = Vt + (size_t)bh * 262144;  // [64 d][4096 s]
  half_t* Ob = O16 + (size_t)(b * 4096 + qt * 128 + qw * 64) * 512 + hh * 64;

  // Q fragments (B-operand): row q = qm*32+lo, elems d = ks*16 + h*8 .. +7
  half8 qa[2][4];
#pragma unroll
  for (int qm = 0; qm < 2; ++qm)
#pragma unroll
    for (int ks = 0; ks < 4; ++ks)
      qa[qm][ks] = *(const half8*)(Qb + (size_t)(qm * 32 + lo) * 512 + ks * 16 + h * 8);

  floatx16 acc[2][2];
#pragma unroll
  for (int qm = 0; qm < 2; ++qm)
#pragma unroll
    for (int dn = 0; dn < 2; ++dn)
#pragma unroll
      for (int r = 0; r < 16; ++r) acc[qm][dn][r] = 0.f;
  float lf[2] = {0.f, 0.f};

  // stage K/V tile t (64 keys) into buffer buf; linear LDS dest, pre-swizzled src
  auto stage = [&](int buf, int t) {
#pragma unroll
    for (int i = 0; i < 2; ++i) {
      int rel = i * 4096 + tid * 16;
      int lg = swz128(rel);
      int row = lg >> 7, inner = (lg & 127) >> 1;
      gload_lds16(Kb + (size_t)(t * 64 + row) * 512 + inner,
                  kb_lds + buf * 4096 + (rel >> 1));
      gload_lds16(Vb + (size_t)row * 4096 + t * 64 + inner,
                  vb_lds + buf * 4096 + (rel >> 1));
    }
  };

  stage(0, 0);
  int cur = 0;

  for (int t = 0; t < 64; ++t) {
    __syncthreads();  // drains staging (vmcnt0) + gates buffer reuse
    if (t < 63) stage(cur ^ 1, t + 1);

    // S^T[key][q] = K.Q^T; wave covers keys kw*32..+32 x q qw*64..+64
    floatx16 s[2];  // [qm]
#pragma unroll
    for (int qm = 0; qm < 2; ++qm)
#pragma unroll
      for (int r = 0; r < 16; ++r) s[qm][r] = 0.f;

#pragma unroll
    for (int ks = 0; ks < 4; ++ks) {
      int byte = ((kw * 32 + lo) << 7) + (ks << 5) + (h << 4);
      half8 ka = *(const half8*)&kb_lds[cur * 4096 + (swz128(byte) >> 1)];
#pragma unroll
      for (int qm = 0; qm < 2; ++qm)
        s[qm] = __builtin_amdgcn_mfma_f32_32x32x16_f16(ka, qa[qm][ks], s[qm], 0, 0, 0);
    }

    // P = exp2(S^T) in-place; in-lane row partial sums; pack to PV A-frags (T12)
    uint4v pa[2][2];
#pragma unroll
    for (int qm = 0; qm < 2; ++qm) {
      float psum = 0.f;
#pragma unroll
      for (int r = 0; r < 16; ++r) {
        float e = __builtin_amdgcn_exp2f(s[qm][r]);
        s[qm][r] = e;
        psum += e;
      }
      lf[qm] += psum;
#pragma unroll
      for (int ksb = 0; ksb < 2; ++ksb) {
        uint x0 = pkrtz(s[qm][8 * ksb + 0], s[qm][8 * ksb + 1]);
        uint x1 = pkrtz(s[qm][8 * ksb + 2], s[qm][8 * ksb + 3]);
        uint y0 = pkrtz(s[qm][8 * ksb + 4], s[qm][8 * ksb + 5]);
        uint y1 = pkrtz(s[qm][8 * ksb + 6], s[qm][8 * ksb + 7]);
        pl32swap(x0, y0);
        pl32swap(x1, y1);
        pa[qm][ksb] = (uint4v){x0, x1, y0, y1};
      }
    }

    // O += P V : A = pa (q rows x 16k), B = V^T rows (d rows x 16k keys)
#pragma unroll
    for (int dn = 0; dn < 2; ++dn)
#pragma unroll
      for (int ks = 0; ks < 2; ++ks) {
        int byte = ((dn * 32 + lo) << 7) + ((kw * 32 + ks * 16 + h * 8) << 1);
        half8 vb = *(const half8*)&vb_lds[cur * 4096 + (swz128(byte) >> 1)];
#pragma unroll
        for (int qm = 0; qm < 2; ++qm)
          acc[qm][dn] =
              __builtin_amdgcn_mfma_f32_32x32x16_f16(as_h8(pa[qm][ks]), vb, acc[qm][dn], 0, 0, 0);
      }

    cur ^= 1;
  }

  // ---- cross-wave (k-half) reduction + normalize + store (v3 verbatim) ----
#pragma unroll
  for (int qm = 0; qm < 2; ++qm) lf[qm] += __shfl_xor(lf[qm], 32);

  float* red = (float*)smem;             // 32 KB: [qw][qm][dn][r][lane]
  float* redl = (float*)(smem + 32768);  // 1 KB: [qw][qm][lane]

  __syncthreads();
  if (kw == 1) {
#pragma unroll
    for (int qm = 0; qm < 2; ++qm) {
      redl[(qw * 2 + qm) * 64 + l] = lf[qm];
#pragma unroll
      for (int dn = 0; dn < 2; ++dn)
#pragma unroll
        for (int r = 0; r < 16; ++r)
          red[((((qw * 2 + qm) * 2 + dn) * 16) + r) * 64 + l] = acc[qm][dn][r];
    }
  }
  __syncthreads();
  if (kw == 0) {
    float inv[2];
#pragma unroll
    for (int qm = 0; qm < 2; ++qm)
      inv[qm] = 1.0f / (lf[qm] + redl[(qw * 2 + qm) * 64 + l]);
#pragma unroll
    for (int qm = 0; qm < 2; ++qm)
#pragma unroll
      for (int r = 0; r < 16; ++r) {
        int ro = (r & 3) + 8 * (r >> 2) + 4 * h;
        float iv = __shfl(inv[qm], ro);
#pragma unroll
        for (int dn = 0; dn < 2; ++dn) {
          float o = (acc[qm][dn][r] + red[((((qw * 2 + qm) * 2 + dn) * 16) + r) * 64 + l]) * iv;
          Ob[(size_t)(qm * 32 + ro) * 512 + dn * 32 + lo] = (half_t)o;
        }
      }
  }
}

extern "C" void kernel_launch(void* const* d_in, const int* in_sizes, int n_in,
                              void* d_out, int out_size, void* d_ws, size_t ws_size,
                              hipStream_t stream) {
  const float* X  = (const float*)d_in[0];
  const float* Wq = (const float*)d_in[1];
  const float* Wk = (const float*)d_in[2];
  const float* Wv = (const float*)d_in[3];
  const float* Wo = (const float*)d_in[4];
  const float* bo = (const float*)d_in[5];
  float* out = (float*)d_out;

  char* ws = (char*)d_ws;
  half_t* X16  = (half_t*)(ws);                 // 8 MB
  half_t* W16  = (half_t*)(ws + 8388608);       // 2 MB (Wq|Wk|Wv|Wo)
  half_t* Q16  = (half_t*)(ws + 10485760);      // 8 MB
  half_t* K16  = (half_t*)(ws + 18874368);      // 8 MB
  half_t* VtW  = (half_t*)(ws + 27262976);      // 8 MB  [B][H][64][4096]
  half_t* O16  = (half_t*)(ws + 35651584);      // 8 MB
  half_t* Wq16 = W16;
  half_t* Wk16 = W16 + 262144;
  half_t* Wv16 = W16 + 524288;
  half_t* Wo16 = W16 + 786432;

  cvt_x_kernel<<<2048, 256, 0, stream>>>(X, X16);
  cvt_w_kernel<<<512, 256, 0, stream>>>(Wq, Wk, Wv, Wo, W16);
  gemm_nt<0><<<512, 256, 0, stream>>>(X16, Wq16, Wk16, Q16, K16, nullptr, nullptr);
  gemm_nt<1><<<256, 256, 0, stream>>>(Wv16, X16, nullptr, VtW, nullptr, nullptr, nullptr);
  attn_kernel<<<512, 256, 0, stream>>>(Q16, K16, VtW, O16);
  gemm_nt<2><<<256, 256, 0, stream>>>(O16, Wo16, nullptr, nullptr, nullptr, out, bo);
}